// Round 3
// baseline (1482.135 us; speedup 1.0000x reference)
//
#include <hip/hip_runtime.h>
#include <math.h>

#define VOCAB   65536
#define HDIM    512
#define MLEN    16
#define NWORDS  8192
#define IHDIM   128      // char emb dim / LSTM input
#define HHDIM   256      // hidden per direction
#define KDIM    384

#define TM 16            // words per block (LSTM)
#define TW 16            // words per block (projection)

// workspace byte offsets
#define B_WP   0u            // [2][12 kt][64 nt][64 lane] uint4 B-fragment weights = 1572864 B
#define B_CEH  1572864u      // [256][64] uint f16x2 char emb = 65536 B
#define B_BC   1638400u      // [2][1024] float combined bias = 8192 B
#define B_PT   1646592u      // [128][512][4] packed proj_w fp32 = 1048576 B
#define B_CHE  2695168u      // [NWORDS][512] fp32 char-path embeddings = 16777216 B
#define B_INT  19472384u     // ints: [0..15] cnt, [16..31] offs, [32..47] cursor, [48] total, [64..] sorted

typedef _Float16 f16x8 __attribute__((ext_vector_type(8)));
typedef float    f32x4 __attribute__((ext_vector_type(4)));

union U4H8 { uint4 u; f16x8 h; };

__device__ __forceinline__ unsigned packh2(float lo, float hi) {
    union { _Float16 h[2]; unsigned u; } v;
    v.h[0] = (_Float16)lo; v.h[1] = (_Float16)hi;
    return v.u;
}

__device__ __forceinline__ float sigf(float x)  { return 1.0f / (1.0f + __expf(-x)); }
__device__ __forceinline__ float tanh_f(float x){ return 1.0f - 2.0f / (__expf(2.0f * x) + 1.0f); }

// ---- pack: B-frag weights (f16), char emb (f16), combined bias, proj ----
__global__ void prep_k(const float* __restrict__ wihf, const float* __restrict__ whhf,
                       const float* __restrict__ bihf, const float* __restrict__ bhhf,
                       const float* __restrict__ wihb, const float* __restrict__ whhb,
                       const float* __restrict__ bihb, const float* __restrict__ bhhb,
                       const float* __restrict__ chemb, const float* __restrict__ projw,
                       char* __restrict__ wsb) {
    int i = blockIdx.x * blockDim.x + threadIdx.x;
    if (i < 98304) {  // 2 dirs * 12 kt * 64 nt * 64 lanes
        int dir = i / 49152, r = i % 49152;
        int kt = r >> 12, r2 = r & 4095, nt = r2 >> 6, lane = r2 & 63;
        const float* wih = dir ? wihb : wihf;
        const float* whh = dir ? whhb : whhf;
        int n  = nt * 16 + (lane & 15);          // gate-unit row (g*256+u == w_ih row)
        int k0 = kt * 32 + (lane >> 4) * 8;      // K position (pairs never straddle 128)
        unsigned q[4];
        #pragma unroll
        for (int jj = 0; jj < 4; ++jj) {
            int k = k0 + 2 * jj;
            float lo = (k     < IHDIM) ? wih[n * IHDIM + k]     : whh[n * HHDIM + (k - IHDIM)];
            float hi = (k + 1 < IHDIM) ? wih[n * IHDIM + k + 1] : whh[n * HHDIM + (k + 1 - IHDIM)];
            q[jj] = packh2(lo, hi);
        }
        ((uint4*)(wsb + B_WP))[i] = make_uint4(q[0], q[1], q[2], q[3]);
    }
    if (i < 16384) {  // char emb f16x2
        int cid = i >> 6, j2 = i & 63;
        ((unsigned*)(wsb + B_CEH))[i] = packh2(chemb[cid * IHDIM + 2 * j2], chemb[cid * IHDIM + 2 * j2 + 1]);
    }
    if (i < 2048) {   // combined bias, n-indexed
        int dir = i >> 10, n = i & 1023;
        ((float*)(wsb + B_BC))[i] = dir ? (bihb[n] + bhhb[n]) : (bihf[n] + bhhf[n]);
    }
    if (i < 262144) { // pT[k4][j][kk] = projw[j][k4*4+kk]
        int k4 = i >> 11, r = i & 2047, j = r >> 2, kk = r & 3;
        ((float*)(wsb + B_PT))[i] = projw[j * HDIM + k4 * 4 + kk];
    }
}

// ---- counting sort of OOV word indices by length (descending) ----
__global__ void count_k(const int* __restrict__ is_oov, const int* __restrict__ lens,
                        int* __restrict__ ip) {
    int n = blockIdx.x * blockDim.x + threadIdx.x;
    if (n < NWORDS && is_oov[n] > 0) atomicAdd(&ip[lens[n] - 1], 1);
}

__global__ void prefix_k(int* __restrict__ ip) {
    if (threadIdx.x == 0) {
        int total = 0;
        for (int b = 15; b >= 0; --b) { ip[16 + b] = total; ip[32 + b] = total; total += ip[b]; }
        ip[48] = total;
    }
}

__global__ void scatter_k(const int* __restrict__ is_oov, const int* __restrict__ lens,
                          int* __restrict__ ip) {
    int n = blockIdx.x * blockDim.x + threadIdx.x;
    if (n < NWORDS && is_oov[n] > 0) {
        int pos = atomicAdd(&ip[32 + lens[n] - 1], 1);
        ip[64 + pos] = n;
    }
}

// ---- MFMA BiLSTM: block = 16 words (one dir); gates via mfma_f32_16x16x32_f16 ----
// Wave w owns units u in [64w, 64w+64) across all 4 gates.
// Z LDS layout: [16 words][392 f16] (cols 0..127 = x_t, 128..383 = h_{t-1}; pad 8 -> 2-way banks).
__global__ __launch_bounds__(256, 2)
void lstm_k(const int* __restrict__ char_ids, const int* __restrict__ lens,
            const char* __restrict__ wsb, const int* __restrict__ ip) {
    const int dir = blockIdx.y;
    const int tid = threadIdx.x;
    const int total = ip[48];
    const int w0 = blockIdx.x * TM;
    if (w0 >= total) return;
    const int wcount = min(TM, total - w0);
    const int* sorted = ip + 64;

    __shared__ int n_s[TM], len_s[TM];
    __shared__ __align__(16) _Float16 Zs[TM][392];   // 12.25 KB

    if (tid < TM) {
        int idx = w0 + min(tid, wcount - 1);
        n_s[tid] = sorted[idx];
        len_s[tid] = (tid < wcount) ? lens[sorted[idx]] : 0;
    }
    for (int i = tid; i < TM * 32; i += 256) {        // zero h region (16 rows x 32 uint4)
        int m = i >> 5, q = i & 31;
        *(uint4*)&Zs[m][128 + q * 8] = make_uint4(0, 0, 0, 0);
    }
    __syncthreads();

    const int wv = tid >> 6, lane = tid & 63, col = lane & 15, quad = lane >> 4;
    const int maxlen = len_s[0];                      // sorted desc
    int len_r[4];
    #pragma unroll
    for (int r = 0; r < 4; ++r) len_r[r] = len_s[quad * 4 + r];

    const uint4* ceh4 = (const uint4*)(wsb + B_CEH);
    auto gather = [&](int t) {                        // Zs[m][0..127] = x_t (f16)
        int m = tid >> 4, q = tid & 15;
        int L = len_s[m];
        int pos = dir ? max(L - 1 - t, 0) : t;
        int cid = char_ids[n_s[m] * MLEN + pos];
        *(uint4*)&Zs[m][q * 8] = ceh4[cid * 16 + q];
    };
    gather(0);

    const uint4* wb = (const uint4*)(wsb + B_WP);
    const float* bc = (const float*)(wsb + B_BC) + dir * 1024;
    float bias[4][4], cst[4][4];
    #pragma unroll
    for (int g = 0; g < 4; ++g)
        #pragma unroll
        for (int c = 0; c < 4; ++c) {
            bias[g][c] = bc[g * 256 + wv * 64 + c * 16 + col];
            cst[g][c] = 0.0f;
        }
    __syncthreads();

    for (int t = 0; t < maxlen; ++t) {
        f32x4 acc[4][4];
        #pragma unroll
        for (int g = 0; g < 4; ++g)
            #pragma unroll
            for (int c = 0; c < 4; ++c) {
                float b = bias[g][c];
                acc[g][c] = (f32x4){b, b, b, b};
            }

        for (int kt = 0; kt < 12; ++kt) {
            // A-frag: A[m=lane&15][k=kt*32+quad*8+j] from LDS (ds_read_b128, 2-way banks)
            const f16x8 af = *(const f16x8*)&Zs[col][kt * 32 + quad * 8];
            const uint4* wkt = wb + ((size_t)(dir * 12 + kt) * 4096) + lane;
            #pragma unroll
            for (int g = 0; g < 4; ++g)
                #pragma unroll
                for (int c = 0; c < 4; ++c) {
                    U4H8 bq; bq.u = wkt[(g * 16 + wv * 4 + c) * 64];
                    acc[g][c] = __builtin_amdgcn_mfma_f32_16x16x32_f16(af, bq.h, acc[g][c], 0, 0, 0);
                }
        }
        __syncthreads();   // all A-frag reads done before h/x overwrite

        #pragma unroll
        for (int c = 0; c < 4; ++c) {
            const int u = wv * 64 + c * 16 + col;
            #pragma unroll
            for (int r = 0; r < 4; ++r) {
                // C/D layout: row m = quad*4 + r, col n = lane&15
                float i_ = sigf(acc[0][c][r]);
                float f_ = sigf(acc[1][c][r]);
                float g_ = tanh_f(acc[2][c][r]);
                float o_ = sigf(acc[3][c][r]);
                float cn = f_ * cst[c][r] + i_ * g_;
                bool msk = (t < len_r[r]);
                cst[c][r] = msk ? cn : cst[c][r];
                if (msk) Zs[quad * 4 + r][128 + u] = (_Float16)(o_ * tanh_f(cn));
            }
        }
        if (t + 1 < maxlen) gather(t + 1);
        __syncthreads();
    }

    float* che = (float*)(wsb + B_CHE);
    for (int i = tid; i < TM * HHDIM; i += 256) {
        int m = i >> 8, u = i & 255;
        if (m < wcount)
            che[(size_t)n_s[m] * HDIM + dir * HHDIM + u] = (float)Zs[m][128 + u];
    }
}

// ---- select (vocab vs char path) + projection (fp32) ----
__global__ __launch_bounds__(256, 2)
void proj_k(const int* __restrict__ word_ids, const int* __restrict__ is_oov,
            const float* __restrict__ word_emb, const char* __restrict__ wsb,
            const float* __restrict__ proj_b, float* __restrict__ out) {
    const int tid = threadIdx.x;
    const int n0 = blockIdx.x * TW;
    __shared__ __align__(16) float4 sel[TW][128];   // 32 KB

    const float* che = (const float*)(wsb + B_CHE);
    for (int f = tid; f < TW * 128; f += 256) {
        int w = f >> 7, k4 = f & 127;
        int n = n0 + w;
        const float4* src = (is_oov[n] > 0) ? (const float4*)(che + (size_t)n * HDIM)
                                            : (const float4*)(word_emb + (size_t)word_ids[n] * HDIM);
        sel[w][k4] = src[k4];
    }
    __syncthreads();

    const float pb0 = proj_b[tid];
    const float pb1 = proj_b[tid + 256];
    float acc0[TW], acc1[TW];
    #pragma unroll
    for (int w = 0; w < TW; ++w) { acc0[w] = pb0; acc1[w] = pb1; }

    const float4* pT4 = (const float4*)(wsb + B_PT);   // pT4[k4*512 + j]
    for (int k4 = 0; k4 < 128; ++k4) {
        const float4 p0 = pT4[k4 * 512 + tid];
        const float4 p1 = pT4[k4 * 512 + tid + 256];
        #pragma unroll
        for (int w = 0; w < TW; ++w) {
            const float4 z = sel[w][k4];
            acc0[w] = fmaf(p0.x, z.x, fmaf(p0.y, z.y, fmaf(p0.z, z.z, fmaf(p0.w, z.w, acc0[w]))));
            acc1[w] = fmaf(p1.x, z.x, fmaf(p1.y, z.y, fmaf(p1.z, z.z, fmaf(p1.w, z.w, acc1[w]))));
        }
    }
    #pragma unroll
    for (int w = 0; w < TW; ++w) {
        out[(size_t)(n0 + w) * HDIM + tid]       = acc0[w];
        out[(size_t)(n0 + w) * HDIM + tid + 256] = acc1[w];
    }
}

extern "C" void kernel_launch(void* const* d_in, const int* in_sizes, int n_in,
                              void* d_out, int out_size, void* d_ws, size_t ws_size,
                              hipStream_t stream) {
    const int*   word_ids  = (const int*)d_in[0];
    const int*   is_oov    = (const int*)d_in[1];
    const int*   char_ids  = (const int*)d_in[2];
    const int*   char_lens = (const int*)d_in[3];
    const float* word_emb  = (const float*)d_in[4];
    const float* char_emb  = (const float*)d_in[5];
    const float* w_ih_f    = (const float*)d_in[6];
    const float* w_hh_f    = (const float*)d_in[7];
    const float* b_ih_f    = (const float*)d_in[8];
    const float* b_hh_f    = (const float*)d_in[9];
    const float* w_ih_b    = (const float*)d_in[10];
    const float* w_hh_b    = (const float*)d_in[11];
    const float* b_ih_b    = (const float*)d_in[12];
    const float* b_hh_b    = (const float*)d_in[13];
    const float* proj_w    = (const float*)d_in[14];
    const float* proj_b    = (const float*)d_in[15];
    float* out = (float*)d_out;
    char*  wsb = (char*)d_ws;
    int*   ip  = (int*)(wsb + B_INT);

    hipMemsetAsync(ip, 0, 256, stream);
    prep_k<<<1024, 256, 0, stream>>>(w_ih_f, w_hh_f, b_ih_f, b_hh_f,
                                     w_ih_b, w_hh_b, b_ih_b, b_hh_b,
                                     char_emb, proj_w, wsb);
    count_k<<<NWORDS / 256, 256, 0, stream>>>(is_oov, char_lens, ip);
    prefix_k<<<1, 64, 0, stream>>>(ip);
    scatter_k<<<NWORDS / 256, 256, 0, stream>>>(is_oov, char_lens, ip);
    lstm_k<<<dim3(NWORDS / TM, 2), 256, 0, stream>>>(char_ids, char_lens, wsb, ip);
    proj_k<<<NWORDS / TW, 256, 0, stream>>>(word_ids, is_oov, word_emb, wsb, proj_b, out);
}

// Round 4
// 521.802 us; speedup vs baseline: 2.8404x; 2.8404x over previous
//
#include <hip/hip_runtime.h>
#include <math.h>

#define VOCAB   65536
#define HDIM    512
#define MLEN    16
#define NWORDS  8192
#define IHDIM   128      // char emb dim / LSTM input
#define HHDIM   256      // hidden per direction

#define TMW 32           // words per LSTM block
#define TW  16           // words per projection block

// workspace byte offsets
#define B_WHH 0u          // [2][8 kt][64 ntg][64 lane] uint4 f16 B-frags = 1 MB
#define B_GXC 1048576u    // [2][256 cid][1024 n] f32 (Wih*emb + b_ih + b_hh) = 2 MB
#define B_PT  3145728u    // [128][512][4] f32 packed proj_w = 1 MB
#define B_CHE 4194304u    // [8192][512] f16 char-path embeddings = 8 MB
#define B_INT 12582912u   // ints: [0..15] cnt, [16..31] offs, [32..47] cursor, [48] total, [64..] sorted

typedef _Float16 f16x8 __attribute__((ext_vector_type(8)));
typedef float    f32x4 __attribute__((ext_vector_type(4)));
union U4H8 { uint4 u; f16x8 h; };

__device__ __forceinline__ unsigned packh2(float lo, float hi) {
    union { _Float16 h[2]; unsigned u; } v;
    v.h[0] = (_Float16)lo; v.h[1] = (_Float16)hi;
    return v.u;
}

__device__ __forceinline__ float sigf(float x)  { return 1.0f / (1.0f + __expf(-x)); }
__device__ __forceinline__ float tanh_f(float x){ return 1.0f - 2.0f / (__expf(2.0f * x) + 1.0f); }

// async global->LDS 16B per lane; lds base must be wave-uniform (writes base + lane*16)
__device__ __forceinline__ void load_lds_128(const void* g, void* l) {
    __builtin_amdgcn_global_load_lds((const __attribute__((address_space(1))) unsigned*)g,
                                     (__attribute__((address_space(3))) unsigned*)l, 16, 0, 0);
}

// ---- pack W_hh into MFMA B-fragment order (f16) + pack proj ----
__global__ void prep_k(const float* __restrict__ whhf, const float* __restrict__ whhb,
                       const float* __restrict__ projw, char* __restrict__ wsb) {
    int i = blockIdx.x * blockDim.x + threadIdx.x;
    if (i < 65536) {   // 2 dirs * 8 kt * 64 ntg * 64 lanes
        int dir = i >> 15, r = i & 32767, kt = r >> 12, r2 = r & 4095, ntg = r2 >> 6, lane = r2 & 63;
        const float* whh = dir ? whhb : whhf;
        int n  = ntg * 16 + (lane & 15);        // gate-major row of w_hh
        int k0 = kt * 32 + (lane >> 4) * 8;     // K position within [0,256)
        unsigned q[4];
        #pragma unroll
        for (int jj = 0; jj < 4; ++jj)
            q[jj] = packh2(whh[n * HHDIM + k0 + 2 * jj], whh[n * HHDIM + k0 + 2 * jj + 1]);
        ((uint4*)(wsb + B_WHH))[i] = make_uint4(q[0], q[1], q[2], q[3]);
    }
    if (i < 262144) {  // pT[k4][j][kk] = projw[j][k4*4+kk]
        int k4 = i >> 11, r = i & 2047, j = r >> 2, kk = r & 3;
        ((float*)(wsb + B_PT))[i] = projw[j * HDIM + k4 * 4 + kk];
    }
}

// ---- gxc[dir][cid][n] = W_ih[n,:] . emb[cid] + b_ih[n] + b_hh[n]  (fp32) ----
__global__ void gxc_k(const float* __restrict__ wihf, const float* __restrict__ wihb,
                      const float* __restrict__ bihf, const float* __restrict__ bhhf,
                      const float* __restrict__ bihb, const float* __restrict__ bhhb,
                      const float* __restrict__ chemb, char* __restrict__ wsb) {
    const int dir = blockIdx.x >> 8, cid = blockIdx.x & 255;
    __shared__ __align__(16) float emb[IHDIM];
    if (threadIdx.x < IHDIM) emb[threadIdx.x] = chemb[cid * IHDIM + threadIdx.x];
    __syncthreads();
    const float* wih = dir ? wihb : wihf;
    const float* bih = dir ? bihb : bihf;
    const float* bhh = dir ? bhhb : bhhf;
    float* gxc = (float*)(wsb + B_GXC) + (size_t)dir * 262144 + (size_t)cid * 1024;
    #pragma unroll
    for (int p = 0; p < 4; ++p) {
        int n = threadIdx.x + p * 256;
        float acc = bih[n] + bhh[n];
        const float4* w4 = (const float4*)(wih + n * IHDIM);
        const float4* e4 = (const float4*)emb;
        #pragma unroll 8
        for (int k4 = 0; k4 < 32; ++k4) {
            float4 w = w4[k4], e = e4[k4];
            acc = fmaf(w.x, e.x, fmaf(w.y, e.y, fmaf(w.z, e.z, fmaf(w.w, e.w, acc))));
        }
        gxc[n] = acc;
    }
}

// ---- counting sort of OOV word indices by length (descending) ----
__global__ void count_k(const int* __restrict__ is_oov, const int* __restrict__ lens,
                        int* __restrict__ ip) {
    int n = blockIdx.x * blockDim.x + threadIdx.x;
    if (n < NWORDS && is_oov[n] > 0) atomicAdd(&ip[lens[n] - 1], 1);
}

__global__ void prefix_k(int* __restrict__ ip) {
    if (threadIdx.x == 0) {
        int total = 0;
        for (int b = 15; b >= 0; --b) { ip[16 + b] = total; ip[32 + b] = total; total += ip[b]; }
        ip[48] = total;
    }
}

__global__ void scatter_k(const int* __restrict__ is_oov, const int* __restrict__ lens,
                          int* __restrict__ ip) {
    int n = blockIdx.x * blockDim.x + threadIdx.x;
    if (n < NWORDS && is_oov[n] > 0) {
        int pos = atomicAdd(&ip[32 + lens[n] - 1], 1);
        ip[64 + pos] = n;
    }
}

// ---- MFMA BiLSTM: 512 thr, 32 words/block, wave-private double-buffered weight DMA ----
// Wave wv owns units u in [wv*32, wv*32+32) across all 4 gates (ntg = g*16 + wv*2 + c).
// GEMM per step: [32 m x 256 k] x [256 k x 1024 n]; x-contribution via gxc C-init.
__global__ __launch_bounds__(512, 2)
void lstm_k(const int* __restrict__ char_ids, const int* __restrict__ lens,
            const char* __restrict__ wsb, const int* __restrict__ ip) {
    const int dir = blockIdx.y;
    const int tid = threadIdx.x;
    const int total = ip[48];
    const int w0 = blockIdx.x * TMW;
    if (w0 >= total) return;
    const int wcount = min(TMW, total - w0);
    const int* sorted = ip + 64;

    __shared__ int n_s[TMW], len_s[TMW];
    __shared__ int cid_s[MLEN][TMW];
    __shared__ __align__(16) _Float16 Zh[TMW][264];     // h state, pad 264 (16.5 KB)
    __shared__ __align__(16) uint4 wbuf[8][2][512];     // per-wave double buffers (128 KB)

    if (tid < TMW) {
        int idx = w0 + min(tid, wcount - 1);
        n_s[tid] = sorted[idx];
        len_s[tid] = (tid < wcount) ? lens[sorted[idx]] : 0;
    }
    for (int i = tid; i < TMW * 132; i += 512) ((unsigned*)Zh)[i] = 0u;   // h0 = 0
    __syncthreads();
    {   // stage char ids (pre-reversed for bwd)
        int m = tid >> 4, t = tid & 15;
        int L = len_s[m];
        int pos = dir ? max(L - 1 - t, 0) : t;
        cid_s[t][m] = char_ids[n_s[m] * MLEN + pos];
    }

    const int wv = tid >> 6, lane = tid & 63, col = lane & 15, quad = lane >> 4;
    int lenr[2][4];
    #pragma unroll
    for (int mt = 0; mt < 2; ++mt)
        #pragma unroll
        for (int r = 0; r < 4; ++r) lenr[mt][r] = len_s[mt * 16 + quad * 4 + r];
    const int maxlen = len_s[0];    // sorted desc

    const uint4* wpg = (const uint4*)(wsb + B_WHH) + (size_t)dir * 32768;   // [kt][ntg][lane]
    const float* gxc = (const float*)(wsb + B_GXC) + (size_t)dir * 262144;

    float cst[2][2][4];   // cell state [c][mt][r]
    #pragma unroll
    for (int c = 0; c < 2; ++c)
        #pragma unroll
        for (int mt = 0; mt < 2; ++mt)
            #pragma unroll
            for (int r = 0; r < 4; ++r) cst[c][mt][r] = 0.0f;

    auto stage = [&](int kt, int buf) {   // wave-private: 8 chunks of 1 KB
        #pragma unroll
        for (int gc = 0; gc < 8; ++gc) {
            int ntg = (gc >> 1) * 16 + wv * 2 + (gc & 1);
            load_lds_128(wpg + (kt * 4096 + ntg * 64 + lane), &wbuf[wv][buf][gc * 64]);
        }
    };
    stage(0, 0);
    __syncthreads();   // cid_s/Zh visible; stage(0) drained by the implicit vmcnt(0)

    for (int t = 0; t < maxlen; ++t) {
        int cids[2][4];
        #pragma unroll
        for (int mt = 0; mt < 2; ++mt)
            #pragma unroll
            for (int r = 0; r < 4; ++r) cids[mt][r] = cid_s[t][mt * 16 + quad * 4 + r];

        f32x4 acc[4][2][2];   // [g][c][mt], C-init = gxc (x-path + biases)
        #pragma unroll
        for (int g = 0; g < 4; ++g)
            #pragma unroll
            for (int c = 0; c < 2; ++c) {
                const int nn = g * 256 + wv * 32 + c * 16 + col;
                #pragma unroll
                for (int mt = 0; mt < 2; ++mt) {
                    f32x4 a;
                    #pragma unroll
                    for (int r = 0; r < 4; ++r) a[r] = gxc[cids[mt][r] * 1024 + nn];
                    acc[g][c][mt] = a;
                }
            }

        #pragma unroll
        for (int kt = 0; kt < 8; ++kt) {
            const int buf = kt & 1;
            stage((kt + 1) & 7, buf ^ 1);               // prefetch (wraps to next step's kt0)
            __builtin_amdgcn_s_waitcnt(0x0F78);         // vmcnt(8): cur buf's DMA done
            f16x8 af0 = *(const f16x8*)&Zh[col][kt * 32 + quad * 8];
            f16x8 af1 = *(const f16x8*)&Zh[16 + col][kt * 32 + quad * 8];
            #pragma unroll
            for (int g = 0; g < 4; ++g)
                #pragma unroll
                for (int c = 0; c < 2; ++c) {
                    U4H8 b; b.u = wbuf[wv][buf][(g * 2 + c) * 64 + lane];
                    acc[g][c][0] = __builtin_amdgcn_mfma_f32_16x16x32_f16(af0, b.h, acc[g][c][0], 0, 0, 0);
                    acc[g][c][1] = __builtin_amdgcn_mfma_f32_16x16x32_f16(af1, b.h, acc[g][c][1], 0, 0, 0);
                }
        }
        __syncthreads();   // all waves' A-reads done before h overwrite

        #pragma unroll
        for (int mt = 0; mt < 2; ++mt)
            #pragma unroll
            for (int r = 0; r < 4; ++r) {
                if (t < lenr[mt][r]) {
                    const int m = mt * 16 + quad * 4 + r;
                    #pragma unroll
                    for (int c = 0; c < 2; ++c) {
                        float i_ = sigf(acc[0][c][mt][r]);
                        float f_ = sigf(acc[1][c][mt][r]);
                        float g_ = tanh_f(acc[2][c][mt][r]);
                        float o_ = sigf(acc[3][c][mt][r]);
                        float cn = f_ * cst[c][mt][r] + i_ * g_;
                        cst[c][mt][r] = cn;
                        Zh[m][wv * 32 + c * 16 + col] = (_Float16)(o_ * tanh_f(cn));
                    }
                }
            }
        __syncthreads();   // h visible before next step's A-reads
    }

    unsigned short* cheh = (unsigned short*)(wsb + B_CHE);
    for (int i = tid; i < TMW * HHDIM; i += 512) {
        int m = i >> 8, u = i & 255;
        if (m < wcount) {
            union { _Float16 h; unsigned short s; } v; v.h = Zh[m][u];
            __builtin_nontemporal_store(v.s, cheh + (size_t)n_s[m] * HDIM + dir * HHDIM + u);
        }
    }
}

// ---- select (vocab vs char path) + projection (fp32) ----
__global__ __launch_bounds__(256, 2)
void proj_k(const int* __restrict__ word_ids, const int* __restrict__ is_oov,
            const float* __restrict__ word_emb, const char* __restrict__ wsb,
            const float* __restrict__ proj_b, float* __restrict__ out) {
    const int tid = threadIdx.x;
    const int n0 = blockIdx.x * TW;
    __shared__ __align__(16) float4 sel[TW][128];   // 32 KB

    for (int f = tid; f < TW * 128; f += 256) {
        int w = f >> 7, k4 = f & 127;
        int n = n0 + w;
        float4 v;
        if (is_oov[n] > 0) {
            const ushort4* src = (const ushort4*)(wsb + B_CHE) + (size_t)n * 128;
            ushort4 hv = src[k4];
            union { unsigned short s; _Float16 h; } a, b, c, d;
            a.s = hv.x; b.s = hv.y; c.s = hv.z; d.s = hv.w;
            v = make_float4((float)a.h, (float)b.h, (float)c.h, (float)d.h);
        } else {
            v = ((const float4*)(word_emb + (size_t)word_ids[n] * HDIM))[k4];
        }
        sel[w][k4] = v;
    }
    __syncthreads();

    const float pb0 = proj_b[tid];
    const float pb1 = proj_b[tid + 256];
    float acc0[TW], acc1[TW];
    #pragma unroll
    for (int w = 0; w < TW; ++w) { acc0[w] = pb0; acc1[w] = pb1; }

    const float4* pT4 = (const float4*)(wsb + B_PT);   // pT4[k4*512 + j]
    for (int k4 = 0; k4 < 128; ++k4) {
        const float4 p0 = pT4[k4 * 512 + tid];
        const float4 p1 = pT4[k4 * 512 + tid + 256];
        #pragma unroll
        for (int w = 0; w < TW; ++w) {
            const float4 z = sel[w][k4];
            acc0[w] = fmaf(p0.x, z.x, fmaf(p0.y, z.y, fmaf(p0.z, z.z, fmaf(p0.w, z.w, acc0[w]))));
            acc1[w] = fmaf(p1.x, z.x, fmaf(p1.y, z.y, fmaf(p1.z, z.z, fmaf(p1.w, z.w, acc1[w]))));
        }
    }
    #pragma unroll
    for (int w = 0; w < TW; ++w) {
        __builtin_nontemporal_store(acc0[w], &out[(size_t)(n0 + w) * HDIM + tid]);
        __builtin_nontemporal_store(acc1[w], &out[(size_t)(n0 + w) * HDIM + tid + 256]);
    }
}

extern "C" void kernel_launch(void* const* d_in, const int* in_sizes, int n_in,
                              void* d_out, int out_size, void* d_ws, size_t ws_size,
                              hipStream_t stream) {
    const int*   word_ids  = (const int*)d_in[0];
    const int*   is_oov    = (const int*)d_in[1];
    const int*   char_ids  = (const int*)d_in[2];
    const int*   char_lens = (const int*)d_in[3];
    const float* word_emb  = (const float*)d_in[4];
    const float* char_emb  = (const float*)d_in[5];
    const float* w_ih_f    = (const float*)d_in[6];
    const float* w_hh_f    = (const float*)d_in[7];
    const float* b_ih_f    = (const float*)d_in[8];
    const float* b_hh_f    = (const float*)d_in[9];
    const float* w_ih_b    = (const float*)d_in[10];
    const float* w_hh_b    = (const float*)d_in[11];
    const float* b_ih_b    = (const float*)d_in[12];
    const float* b_hh_b    = (const float*)d_in[13];
    const float* proj_w    = (const float*)d_in[14];
    const float* proj_b    = (const float*)d_in[15];
    float* out = (float*)d_out;
    char*  wsb = (char*)d_ws;
    int*   ip  = (int*)(wsb + B_INT);

    hipMemsetAsync(ip, 0, 256, stream);
    prep_k<<<1024, 256, 0, stream>>>(w_hh_f, w_hh_b, proj_w, wsb);
    gxc_k<<<512, 256, 0, stream>>>(w_ih_f, w_ih_b, b_ih_f, b_hh_f, b_ih_b, b_hh_b, char_emb, wsb);
    count_k<<<NWORDS / 256, 256, 0, stream>>>(is_oov, char_lens, ip);
    prefix_k<<<1, 64, 0, stream>>>(ip);
    scatter_k<<<NWORDS / 256, 256, 0, stream>>>(is_oov, char_lens, ip);
    lstm_k<<<dim3(NWORDS / TMW, 2), 512, 0, stream>>>(char_ids, char_lens, wsb, ip);
    proj_k<<<NWORDS / TW, 256, 0, stream>>>(word_ids, is_oov, word_emb, wsb, proj_b, out);
}

// Round 5
// 474.317 us; speedup vs baseline: 3.1248x; 1.1001x over previous
//
#include <hip/hip_runtime.h>
#include <math.h>

#define VOCAB   65536
#define HDIM    512
#define MLEN    16
#define NWORDS  8192
#define IHDIM   128      // char emb dim / LSTM input
#define HHDIM   256      // hidden per direction

#define TMW 32           // words per LSTM block
#define TP  32           // words per projection block

// workspace byte offsets
#define B_WHH 0u          // 1 MB: [2][8 kt][64 ntg][64 lane] uint4 f16 W_hh B-frags
#define B_GX2 1048576u    // 4 MB: [2][256 cid][512 tid] uint4 = 8 f16 (j = g*2+c)
#define B_PBF 5242880u    // 512 KB: [16 kt][32 nt][64 lane] uint4 f16 proj B-frags
#define B_PBB 5767168u    // 2 KB: proj bias f32[512]
#define B_CHE 5769216u    // 8 MB: [8192][512] f16 char-path embeddings
#define B_INT 14157824u   // ints: [0..15] cnt, [16..31] offs, [32..47] cursor, [48] total, [64..] sorted

typedef _Float16 f16x8 __attribute__((ext_vector_type(8)));
typedef float    f32x4 __attribute__((ext_vector_type(4)));
union U4H8 { uint4 u; f16x8 h; _Float16 e[8]; };

__device__ __forceinline__ unsigned packh2(float lo, float hi) {
    union { _Float16 h[2]; unsigned u; } v;
    v.h[0] = (_Float16)lo; v.h[1] = (_Float16)hi;
    return v.u;
}

__device__ __forceinline__ float sigf(float x)  { return 1.0f / (1.0f + __expf(-x)); }
__device__ __forceinline__ float tanh_f(float x){ return 1.0f - 2.0f / (__expf(2.0f * x) + 1.0f); }

// async global->LDS 16B per lane; lds base wave-uniform (writes base + lane*16)
__device__ __forceinline__ void load_lds_128(const void* g, void* l) {
    __builtin_amdgcn_global_load_lds((const __attribute__((address_space(1))) unsigned*)g,
                                     (__attribute__((address_space(3))) unsigned*)l, 16, 0, 0);
}

// ---- pack W_hh B-frags, proj B-frags, proj bias ----
__global__ void prep_k(const float* __restrict__ whhf, const float* __restrict__ whhb,
                       const float* __restrict__ projw, const float* __restrict__ projb,
                       char* __restrict__ wsb) {
    int i = blockIdx.x * blockDim.x + threadIdx.x;
    if (i < 65536) {   // 2 dirs * 8 kt * 64 ntg * 64 lanes
        int dir = i >> 15, r = i & 32767, kt = r >> 12, r2 = r & 4095, ntg = r2 >> 6, lane = r2 & 63;
        const float* whh = dir ? whhb : whhf;
        int n  = ntg * 16 + (lane & 15);
        int k0 = kt * 32 + (lane >> 4) * 8;
        unsigned q[4];
        #pragma unroll
        for (int jj = 0; jj < 4; ++jj)
            q[jj] = packh2(whh[n * HHDIM + k0 + 2 * jj], whh[n * HHDIM + k0 + 2 * jj + 1]);
        ((uint4*)(wsb + B_WHH))[i] = make_uint4(q[0], q[1], q[2], q[3]);
    }
    if (i < 32768) {   // 16 kt * 32 nt * 64 lanes (proj: B[k][j] = projw[j][k])
        int kt = i >> 11, r = i & 2047, nt = r >> 6, lane = r & 63;
        int j  = nt * 16 + (lane & 15);
        int k0 = kt * 32 + (lane >> 4) * 8;
        unsigned q[4];
        #pragma unroll
        for (int jj = 0; jj < 4; ++jj)
            q[jj] = packh2(projw[j * HDIM + k0 + 2 * jj], projw[j * HDIM + k0 + 2 * jj + 1]);
        ((uint4*)(wsb + B_PBF))[i] = make_uint4(q[0], q[1], q[2], q[3]);
    }
    if (i < 512) ((float*)(wsb + B_PBB))[i] = projb[i];
}

// ---- gxc2[dir][cid][tid] = 16B of thread-major f16 (W_ih.emb + b_ih + b_hh) ----
__global__ void gxc_k(const float* __restrict__ wihf, const float* __restrict__ wihb,
                      const float* __restrict__ bihf, const float* __restrict__ bhhf,
                      const float* __restrict__ bihb, const float* __restrict__ bhhb,
                      const float* __restrict__ chemb, char* __restrict__ wsb) {
    const int dir = blockIdx.x >> 8, cid = blockIdx.x & 255;
    __shared__ __align__(16) float emb[IHDIM];
    __shared__ float gxl[1024];
    if (threadIdx.x < IHDIM) emb[threadIdx.x] = chemb[cid * IHDIM + threadIdx.x];
    __syncthreads();
    const float* wih = dir ? wihb : wihf;
    const float* bih = dir ? bihb : bihf;
    const float* bhh = dir ? bhhb : bhhf;
    #pragma unroll
    for (int p = 0; p < 4; ++p) {
        int n = threadIdx.x + p * 256;
        float acc = bih[n] + bhh[n];
        const float4* w4 = (const float4*)(wih + n * IHDIM);
        const float4* e4 = (const float4*)emb;
        #pragma unroll 8
        for (int k4 = 0; k4 < 32; ++k4) {
            float4 w = w4[k4], e = e4[k4];
            acc = fmaf(w.x, e.x, fmaf(w.y, e.y, fmaf(w.z, e.z, fmaf(w.w, e.w, acc))));
        }
        gxl[n] = acc;
    }
    __syncthreads();
    uint4* outp = (uint4*)(wsb + B_GX2) + (size_t)(dir * 256 + cid) * 512;
    #pragma unroll
    for (int s = 0; s < 2; ++s) {
        int tid2 = threadIdx.x + s * 256;
        int wv = tid2 >> 6, col = tid2 & 15;
        U4H8 v;
        #pragma unroll
        for (int g = 0; g < 4; ++g)
            #pragma unroll
            for (int c = 0; c < 2; ++c)
                v.e[g * 2 + c] = (_Float16)gxl[g * 256 + wv * 32 + c * 16 + col];
        outp[tid2] = v.u;
    }
}

// ---- counting sort of OOV word indices by length (descending) ----
__global__ void count_k(const int* __restrict__ is_oov, const int* __restrict__ lens,
                        int* __restrict__ ip) {
    int n = blockIdx.x * blockDim.x + threadIdx.x;
    if (n < NWORDS && is_oov[n] > 0) atomicAdd(&ip[lens[n] - 1], 1);
}

__global__ void prefix_k(int* __restrict__ ip) {
    if (threadIdx.x == 0) {
        int total = 0;
        for (int b = 15; b >= 0; --b) { ip[16 + b] = total; ip[32 + b] = total; total += ip[b]; }
        ip[48] = total;
    }
}

__global__ void scatter_k(const int* __restrict__ is_oov, const int* __restrict__ lens,
                          int* __restrict__ ip) {
    int n = blockIdx.x * blockDim.x + threadIdx.x;
    if (n < NWORDS && is_oov[n] > 0) {
        int pos = atomicAdd(&ip[32 + lens[n] - 1], 1);
        ip[64 + pos] = n;
    }
}

// ---- MFMA BiLSTM: 512 thr, 32 words/block; C-init via one 16B gx load per (mt,r) ----
__global__ __launch_bounds__(512, 2)
void lstm_k(const int* __restrict__ char_ids, const int* __restrict__ lens,
            const char* __restrict__ wsb, const int* __restrict__ ip) {
    const int dir = blockIdx.y;
    const int tid = threadIdx.x;
    const int total = ip[48];
    const int w0 = blockIdx.x * TMW;
    if (w0 >= total) return;
    const int wcount = min(TMW, total - w0);
    const int* sorted = ip + 64;

    __shared__ int n_s[TMW], len_s[TMW];
    __shared__ int cid_s[MLEN][TMW];
    __shared__ __align__(16) _Float16 Zh[TMW][264];     // 16.5 KB
    __shared__ __align__(16) uint4 wbuf[8][2][512];     // 128 KB

    if (tid < TMW) {
        int idx = w0 + min(tid, wcount - 1);
        n_s[tid] = sorted[idx];
        len_s[tid] = (tid < wcount) ? lens[sorted[idx]] : 0;
    }
    for (int i = tid; i < TMW * 132; i += 512) ((unsigned*)Zh)[i] = 0u;   // h0 = 0
    __syncthreads();
    {   // stage char ids (pre-reversed for bwd)
        int m = tid >> 4, t = tid & 15;
        int L = len_s[m];
        int pos = dir ? max(L - 1 - t, 0) : t;
        cid_s[t][m] = char_ids[n_s[m] * MLEN + pos];
    }

    const int wv = tid >> 6, lane = tid & 63, col = lane & 15, quad = lane >> 4;
    int lenr[2][4];
    #pragma unroll
    for (int mt = 0; mt < 2; ++mt)
        #pragma unroll
        for (int r = 0; r < 4; ++r) lenr[mt][r] = len_s[mt * 16 + quad * 4 + r];
    const int maxlen = len_s[0];    // sorted desc

    const uint4* wpg = (const uint4*)(wsb + B_WHH) + (size_t)dir * 32768;   // [kt][ntg][lane]
    const uint4* gx2 = (const uint4*)(wsb + B_GX2) + (size_t)dir * 131072;  // [cid][tid]

    float cst[2][2][4];   // [c][mt][r]
    #pragma unroll
    for (int c = 0; c < 2; ++c)
        #pragma unroll
        for (int mt = 0; mt < 2; ++mt)
            #pragma unroll
            for (int r = 0; r < 4; ++r) cst[c][mt][r] = 0.0f;

    auto stage = [&](int kt, int buf) {   // wave-private: 8 chunks of 1 KB
        #pragma unroll
        for (int gc = 0; gc < 8; ++gc) {
            int ntg = (gc >> 1) * 16 + wv * 2 + (gc & 1);
            load_lds_128(wpg + (kt * 4096 + ntg * 64 + lane), &wbuf[wv][buf][gc * 64]);
        }
    };
    stage(0, 0);
    __syncthreads();

    for (int t = 0; t < maxlen; ++t) {
        // C-init: one coalesced 16B load per (mt,r), thread-major packed
        U4H8 gq[2][4];
        #pragma unroll
        for (int mt = 0; mt < 2; ++mt)
            #pragma unroll
            for (int r = 0; r < 4; ++r)
                gq[mt][r].u = gx2[(size_t)cid_s[t][mt * 16 + quad * 4 + r] * 512 + tid];

        f32x4 acc[4][2][2];   // [g][c][mt]
        #pragma unroll
        for (int g = 0; g < 4; ++g)
            #pragma unroll
            for (int c = 0; c < 2; ++c)
                #pragma unroll
                for (int mt = 0; mt < 2; ++mt) {
                    f32x4 a;
                    #pragma unroll
                    for (int r = 0; r < 4; ++r) a[r] = (float)gq[mt][r].e[g * 2 + c];
                    acc[g][c][mt] = a;
                }

        #pragma unroll
        for (int kt = 0; kt < 8; ++kt) {
            const int buf = kt & 1;
            stage((kt + 1) & 7, buf ^ 1);               // prefetch next slice
            __builtin_amdgcn_s_waitcnt(0x0F78);         // vmcnt(8): cur buf's DMA done
            f16x8 af0 = *(const f16x8*)&Zh[col][kt * 32 + quad * 8];
            f16x8 af1 = *(const f16x8*)&Zh[16 + col][kt * 32 + quad * 8];
            #pragma unroll
            for (int g = 0; g < 4; ++g)
                #pragma unroll
                for (int c = 0; c < 2; ++c) {
                    U4H8 b; b.u = wbuf[wv][buf][(g * 2 + c) * 64 + lane];
                    acc[g][c][0] = __builtin_amdgcn_mfma_f32_16x16x32_f16(af0, b.h, acc[g][c][0], 0, 0, 0);
                    acc[g][c][1] = __builtin_amdgcn_mfma_f32_16x16x32_f16(af1, b.h, acc[g][c][1], 0, 0, 0);
                }
        }
        __syncthreads();   // all waves' A-reads done before h overwrite

        #pragma unroll
        for (int mt = 0; mt < 2; ++mt)
            #pragma unroll
            for (int r = 0; r < 4; ++r) {
                if (t < lenr[mt][r]) {
                    const int m = mt * 16 + quad * 4 + r;
                    #pragma unroll
                    for (int c = 0; c < 2; ++c) {
                        float i_ = sigf(acc[0][c][mt][r]);
                        float f_ = sigf(acc[1][c][mt][r]);
                        float g_ = tanh_f(acc[2][c][mt][r]);
                        float o_ = sigf(acc[3][c][mt][r]);
                        float cn = f_ * cst[c][mt][r] + i_ * g_;
                        cst[c][mt][r] = cn;
                        Zh[m][wv * 32 + c * 16 + col] = (_Float16)(o_ * tanh_f(cn));
                    }
                }
            }
        __syncthreads();   // h visible before next step's A-reads
    }

    unsigned short* cheh = (unsigned short*)(wsb + B_CHE);
    for (int i = tid; i < TMW * HHDIM; i += 512) {
        int m = i >> 8, u = i & 255;
        if (m < wcount) {
            union { _Float16 h; unsigned short s; } v; v.h = Zh[m][u];
            __builtin_nontemporal_store(v.s, cheh + (size_t)n_s[m] * HDIM + dir * HHDIM + u);
        }
    }
}

// ---- select + projection via f16 MFMA: 32 words/block, 512 thr ----
__global__ __launch_bounds__(512, 2)
void proj_k(const int* __restrict__ word_ids, const int* __restrict__ is_oov,
            const float* __restrict__ word_emb, const char* __restrict__ wsb,
            float* __restrict__ out) {
    const int tid = threadIdx.x;
    const int n0 = blockIdx.x * TP;
    __shared__ __align__(16) _Float16 Zp[TP][520];   // 33.3 KB

    for (int f = tid; f < TP * 128; f += 512) {      // 128 segs of 4 elems per word
        int w = f >> 7, s4 = f & 127;
        int n = n0 + w;
        if (is_oov[n] > 0) {
            ushort4 hv = ((const ushort4*)((const unsigned short*)(wsb + B_CHE) + (size_t)n * HDIM))[s4];
            *(ushort4*)&Zp[w][s4 * 4] = hv;
        } else {
            float4 v = ((const float4*)(word_emb + (size_t)word_ids[n] * HDIM))[s4];
            Zp[w][s4 * 4 + 0] = (_Float16)v.x;
            Zp[w][s4 * 4 + 1] = (_Float16)v.y;
            Zp[w][s4 * 4 + 2] = (_Float16)v.z;
            Zp[w][s4 * 4 + 3] = (_Float16)v.w;
        }
    }
    __syncthreads();

    const int wv = tid >> 6, lane = tid & 63, col = lane & 15, quad = lane >> 4;
    const float* pbb = (const float*)(wsb + B_PBB);
    f32x4 acc[4][2];
    #pragma unroll
    for (int c = 0; c < 4; ++c) {
        float b = pbb[wv * 64 + c * 16 + col];
        acc[c][0] = (f32x4){b, b, b, b};
        acc[c][1] = (f32x4){b, b, b, b};
    }

    const uint4* pbf = (const uint4*)(wsb + B_PBF);
    #pragma unroll
    for (int kt = 0; kt < 16; ++kt) {
        f16x8 af0 = *(const f16x8*)&Zp[col][kt * 32 + quad * 8];
        f16x8 af1 = *(const f16x8*)&Zp[16 + col][kt * 32 + quad * 8];
        #pragma unroll
        for (int c = 0; c < 4; ++c) {
            U4H8 b; b.u = pbf[(size_t)kt * 2048 + (wv * 4 + c) * 64 + lane];
            acc[c][0] = __builtin_amdgcn_mfma_f32_16x16x32_f16(af0, b.h, acc[c][0], 0, 0, 0);
            acc[c][1] = __builtin_amdgcn_mfma_f32_16x16x32_f16(af1, b.h, acc[c][1], 0, 0, 0);
        }
    }

    #pragma unroll
    for (int mt = 0; mt < 2; ++mt)
        #pragma unroll
        for (int r = 0; r < 4; ++r) {
            const size_t m = n0 + mt * 16 + quad * 4 + r;
            #pragma unroll
            for (int c = 0; c < 4; ++c)
                __builtin_nontemporal_store(acc[c][mt][r], &out[m * HDIM + wv * 64 + c * 16 + col]);
        }
}

extern "C" void kernel_launch(void* const* d_in, const int* in_sizes, int n_in,
                              void* d_out, int out_size, void* d_ws, size_t ws_size,
                              hipStream_t stream) {
    const int*   word_ids  = (const int*)d_in[0];
    const int*   is_oov    = (const int*)d_in[1];
    const int*   char_ids  = (const int*)d_in[2];
    const int*   char_lens = (const int*)d_in[3];
    const float* word_emb  = (const float*)d_in[4];
    const float* char_emb  = (const float*)d_in[5];
    const float* w_ih_f    = (const float*)d_in[6];
    const float* w_hh_f    = (const float*)d_in[7];
    const float* b_ih_f    = (const float*)d_in[8];
    const float* b_hh_f    = (const float*)d_in[9];
    const float* w_ih_b    = (const float*)d_in[10];
    const float* w_hh_b    = (const float*)d_in[11];
    const float* b_ih_b    = (const float*)d_in[12];
    const float* b_hh_b    = (const float*)d_in[13];
    const float* proj_w    = (const float*)d_in[14];
    const float* proj_b    = (const float*)d_in[15];
    float* out = (float*)d_out;
    char*  wsb = (char*)d_ws;
    int*   ip  = (int*)(wsb + B_INT);

    hipMemsetAsync(ip, 0, 256, stream);
    prep_k<<<256, 256, 0, stream>>>(w_hh_f, w_hh_b, proj_w, proj_b, wsb);
    gxc_k<<<512, 256, 0, stream>>>(w_ih_f, w_ih_b, b_ih_f, b_hh_f, b_ih_b, b_hh_b, char_emb, wsb);
    count_k<<<NWORDS / 256, 256, 0, stream>>>(is_oov, char_lens, ip);
    prefix_k<<<1, 64, 0, stream>>>(ip);
    scatter_k<<<NWORDS / 256, 256, 0, stream>>>(is_oov, char_lens, ip);
    lstm_k<<<dim3(NWORDS / TMW, 2), 512, 0, stream>>>(char_ids, char_lens, wsb, ip);
    proj_k<<<NWORDS / TP, 512, 0, stream>>>(word_ids, is_oov, word_emb, wsb, out);
}